// Round 1
// baseline (875.193 us; speedup 1.0000x reference)
//
#include <hip/hip_runtime.h>
#include <cstdint>
#include <cstddef>

typedef unsigned short u16;
typedef unsigned int u32;

typedef __bf16 bf16x8 __attribute__((ext_vector_type(8)));
typedef float f32x4 __attribute__((ext_vector_type(4)));

__device__ __forceinline__ u16 f2bf(float f) {
  union { float f; u32 u; } v; v.f = f;
  u32 r = v.u + 0x7fffu + ((v.u >> 16) & 1u);   // RNE
  return (u16)(r >> 16);
}
__device__ __forceinline__ float bf2f(u16 h) {
  union { u32 u; float f; } v; v.u = ((u32)h) << 16;
  return v.f;
}

// async global->LDS, 16B per lane; LDS dest = wave-uniform base + lane*16
__device__ __forceinline__ void gld16(const u16* g, u16* l) {
  __builtin_amdgcn_global_load_lds((const __attribute__((address_space(1))) u32*)g,
                                   (__attribute__((address_space(3))) u32*)l,
                                   16, 0, 0);
}

// ---------------------------------------------------------------------------
// GEMM: C(M,N) = A(M,K)bf16 * Bt(N,K)bf16^T + bias, 128x128x32 tiles.
// LDS chunk swizzle: chunk(r,c) stored at slot r*4 + (c ^ ((r>>1)&3)).
// ---------------------------------------------------------------------------
template<bool OUT_F32>
__global__ __launch_bounds__(256)
void gemm_bt(const u16* __restrict__ A, const u16* __restrict__ Bt,
             const float* __restrict__ bias, void* __restrict__ C,
             int M, int N, int K) {
  __shared__ __attribute__((aligned(16))) u16 As[128*32];
  __shared__ __attribute__((aligned(16))) u16 Bs[128*32];
  const int tid  = threadIdx.x;
  const int lane = tid & 63;
  const int wave = tid >> 6;
  const int wm = wave >> 1, wn = wave & 1;
  const int bn = blockIdx.x * 128;
  const int bm = blockIdx.y * 128;
  const int kq = lane >> 4, ml = lane & 15;

  f32x4 acc[4][4] = {};

  for (int k0 = 0; k0 < K; k0 += 32) {
    __syncthreads();
#pragma unroll
    for (int j = 0; j < 2; ++j) {
      int s = wave*128 + j*64 + lane;
      int r = s >> 2;
      int c = (s & 3) ^ ((r >> 1) & 3);
      gld16(A  + (size_t)(bm + r)*K + k0 + c*8, As + (size_t)(wave*128 + j*64)*8);
      gld16(Bt + (size_t)(bn + r)*K + k0 + c*8, Bs + (size_t)(wave*128 + j*64)*8);
    }
    __syncthreads();
    bf16x8 af[4], bfr[4];
#pragma unroll
    for (int t = 0; t < 4; ++t) {
      int ra = wm*64 + t*16 + ml;
      af[t]  = *(const bf16x8*)(As + (size_t)(ra*4 + (kq ^ ((ra >> 1) & 3)))*8);
      int rb = wn*64 + t*16 + ml;
      bfr[t] = *(const bf16x8*)(Bs + (size_t)(rb*4 + (kq ^ ((rb >> 1) & 3)))*8);
    }
#pragma unroll
    for (int i = 0; i < 4; ++i)
#pragma unroll
      for (int j = 0; j < 4; ++j)
        acc[i][j] = __builtin_amdgcn_mfma_f32_16x16x32_bf16(af[i], bfr[j], acc[i][j], 0, 0, 0);
  }

  // C/D layout: col = lane&15, row = (lane>>4)*4 + reg   [m89/m91 verified]
#pragma unroll
  for (int i = 0; i < 4; ++i) {
    int rg0 = bm + wm*64 + i*16 + kq*4;
#pragma unroll
    for (int j = 0; j < 4; ++j) {
      int cg = bn + wn*64 + j*16 + ml;
      float bv = bias[cg];
#pragma unroll
      for (int r = 0; r < 4; ++r) {
        float v = acc[i][j][r] + bv;
        if (OUT_F32) ((float*)C)[(size_t)(rg0 + r)*N + cg] = v;
        else         ((u16*)C)[(size_t)(rg0 + r)*N + cg]   = f2bf(v);
      }
    }
  }
}

// ---------------------------------------------------------------------------
// Flash attention: grid (qt=16, b*32+head=128), block 256 (4 waves x 16 rows).
// Q pre-scaled by (1/sqrt(d))*log2(e); softmax via exp2.
// ---------------------------------------------------------------------------
__global__ __launch_bounds__(256)
void attn(const u16* __restrict__ Q, const u16* __restrict__ K,
          const u16* __restrict__ V, u16* __restrict__ ctx) {
  __shared__ __attribute__((aligned(16))) u16 Qs[64*128];
  __shared__ __attribute__((aligned(16))) u16 Ks[64*128];
  __shared__ __attribute__((aligned(16))) u16 Vs[128*64];
  __shared__ __attribute__((aligned(16))) u16 Ps[4][16*72];  // pad 8: conflict-free A-reads
  const int qt  = blockIdx.x;
  const int bh  = blockIdx.y;
  const int b   = bh >> 5;
  const int kvh = bh & 3;
  const int tid = threadIdx.x;
  const int lane = tid & 63;
  const int wave = tid >> 6;
  const int kq = lane >> 4, ml = lane & 15;

  const u16* Qg = Q + ((size_t)bh*1024 + qt*64)*128;
  const u16* Kg = K + ((size_t)(b*4 + kvh))*1024*128;
  const u16* Vg = V + ((size_t)(b*4 + kvh))*128*1024;

  // stage Q tile (64x128), swizzle slot = r*16 + (c ^ (r&7))
#pragma unroll
  for (int j = 0; j < 4; ++j) {
    int s = wave*256 + j*64 + lane;
    int r = s >> 4, c = (s & 15) ^ (r & 7);
    gld16(Qg + (size_t)r*128 + c*8, Qs + (size_t)(wave*256 + j*64)*8);
  }

  f32x4 o[8] = {};
  float m_i[4] = {-1e30f, -1e30f, -1e30f, -1e30f};
  float l_i[4] = {0.f, 0.f, 0.f, 0.f};

  for (int kt = 0; kt <= qt; ++kt) {
    __syncthreads();
#pragma unroll
    for (int j = 0; j < 4; ++j) {              // K tile 64x128
      int s = wave*256 + j*64 + lane;
      int r = s >> 4, c = (s & 15) ^ (r & 7);
      gld16(Kg + ((size_t)(kt*64 + r))*128 + c*8, Ks + (size_t)(wave*256 + j*64)*8);
    }
#pragma unroll
    for (int j = 0; j < 4; ++j) {              // V^T tile 128x64, slot = d*8 + (c ^ (d&7))
      int s = wave*256 + j*64 + lane;
      int d = s >> 3, c = (s & 7) ^ (d & 7);
      gld16(Vg + (size_t)d*1024 + kt*64 + c*8, Vs + (size_t)(wave*256 + j*64)*8);
    }
    __syncthreads();

    // S = Q * K^T  (16 rows x 64 cols per wave)
    f32x4 sf[4] = {};
#pragma unroll
    for (int ks = 0; ks < 4; ++ks) {
      int rq = wave*16 + ml;
      int cq = ks*4 + kq;
      bf16x8 aq = *(const bf16x8*)(Qs + (size_t)(rq*16 + (cq ^ (rq & 7)))*8);
#pragma unroll
      for (int nt = 0; nt < 4; ++nt) {
        int rk = nt*16 + ml;
        bf16x8 bk = *(const bf16x8*)(Ks + (size_t)(rk*16 + (cq ^ (rk & 7)))*8);
        sf[nt] = __builtin_amdgcn_mfma_f32_16x16x32_bf16(aq, bk, sf[nt], 0, 0, 0);
      }
    }

    const int i0 = qt*64 + wave*16 + kq*4;     // global q row of reg 0
    if (kt == qt) {                            // causal mask on diagonal tile
#pragma unroll
      for (int nt = 0; nt < 4; ++nt) {
        int jg = kt*64 + nt*16 + ml;
#pragma unroll
        for (int r = 0; r < 4; ++r)
          if (jg > i0 + r) sf[nt][r] = -1e30f;
      }
    }
    float rmax[4] = {-1e30f, -1e30f, -1e30f, -1e30f};
#pragma unroll
    for (int nt = 0; nt < 4; ++nt)
#pragma unroll
      for (int r = 0; r < 4; ++r)
        rmax[r] = fmaxf(rmax[r], sf[nt][r]);
#pragma unroll
    for (int r = 0; r < 4; ++r) {              // row-reduce across the 16 col-lanes
      float v = rmax[r];
      v = fmaxf(v, __shfl_xor(v, 1));
      v = fmaxf(v, __shfl_xor(v, 2));
      v = fmaxf(v, __shfl_xor(v, 4));
      v = fmaxf(v, __shfl_xor(v, 8));
      float mo = m_i[r];
      float mn = fmaxf(mo, v);
      m_i[r] = mn;
      rmax[r] = exp2f(mo - mn);                // alpha
    }
    float rsum[4] = {0.f, 0.f, 0.f, 0.f};
#pragma unroll
    for (int nt = 0; nt < 4; ++nt)
#pragma unroll
      for (int r = 0; r < 4; ++r) {
        float p = exp2f(sf[nt][r] - m_i[r]);
        rsum[r] += p;
        Ps[wave][(kq*4 + r)*72 + nt*16 + ml] = f2bf(p);
      }
#pragma unroll
    for (int r = 0; r < 4; ++r) {
      float v = rsum[r];
      v += __shfl_xor(v, 1);
      v += __shfl_xor(v, 2);
      v += __shfl_xor(v, 4);
      v += __shfl_xor(v, 8);
      l_i[r] = l_i[r]*rmax[r] + v;
    }
#pragma unroll
    for (int dt = 0; dt < 8; ++dt)
#pragma unroll
      for (int r = 0; r < 4; ++r)
        o[dt][r] *= rmax[r];
    __syncthreads();                           // P visible before PV reads

    // O += P(16x64) * V(64x128)
#pragma unroll
    for (int ks = 0; ks < 2; ++ks) {
      bf16x8 ap = *(const bf16x8*)(&Ps[wave][ml*72 + ks*32 + kq*8]);
#pragma unroll
      for (int dt = 0; dt < 8; ++dt) {
        int dv = dt*16 + ml;
        int cv = ks*4 + kq;
        bf16x8 bv = *(const bf16x8*)(Vs + (size_t)(dv*8 + (cv ^ (dv & 7)))*8);
        o[dt] = __builtin_amdgcn_mfma_f32_16x16x32_bf16(ap, bv, o[dt], 0, 0, 0);
      }
    }
  }

  const int head = bh & 31;
  float inv[4];
#pragma unroll
  for (int r = 0; r < 4; ++r) inv[r] = 1.f / l_i[r];
  size_t row0 = (size_t)b*1024 + qt*64 + wave*16 + kq*4;
#pragma unroll
  for (int dt = 0; dt < 8; ++dt) {
    int cg = head*128 + dt*16 + ml;
#pragma unroll
    for (int r = 0; r < 4; ++r)
      ctx[(row0 + r)*4096 + cg] = f2bf(o[dt][r]*inv[r]);
  }
}

// ---------------------------------------------------------------------------
// prep kernels
// ---------------------------------------------------------------------------
__global__ void castx(const float* __restrict__ x, u16* __restrict__ xb) {
  size_t i = ((size_t)blockIdx.x*256 + threadIdx.x)*4;
  float4 v = *(const float4*)(x + i);
  u16 o0 = f2bf(v.x), o1 = f2bf(v.y), o2 = f2bf(v.z), o3 = f2bf(v.w);
  ushort4 o; o.x = o0; o.y = o1; o.z = o2; o.w = o3;
  *(ushort4*)(xb + i) = o;
}

// W (K,N) f32 -> Wt (N,K) bf16, 32x32 LDS tile
__global__ void wtrans(const float* __restrict__ W, u16* __restrict__ Wt, int K, int N) {
  __shared__ u16 t[32][40];
  const int n0 = blockIdx.x*32, k0 = blockIdx.y*32;
  const int tid = threadIdx.x;
  const int r = tid >> 3, c4 = (tid & 7)*4;
  const float* src = W + (size_t)(k0 + r)*N + n0 + c4;
#pragma unroll
  for (int i = 0; i < 4; ++i) t[r][c4 + i] = f2bf(src[i]);
  __syncthreads();
  u16* dst = Wt + (size_t)(n0 + r)*K + k0 + c4;
#pragma unroll
  for (int i = 0; i < 4; ++i) dst[i] = t[c4 + i][r];
}

__global__ void packbias(const float* __restrict__ bq, const float* __restrict__ bk,
                         const float* __restrict__ bv, float* __restrict__ out) {
  int i = blockIdx.x*256 + threadIdx.x;
  float v;
  if (i < 4096)      v = bq[i];
  else if (i < 4608) v = bk[i - 4096];
  else               v = bv[i - 4608];
  out[i] = v;
}

// q cols of qkv_lin (ld 5120) -> (b, head, n, d) with RoPE, scaled by (1/sqrt(d))*log2e
__global__ void rope_q(const u16* __restrict__ qkv, u16* __restrict__ qr) {
  int idx = blockIdx.x*256 + threadIdx.x;   // 8388608 pairs
  int dp = idx & 63;
  int head = (idx >> 6) & 31;
  int n = (idx >> 11) & 1023;
  int b = idx >> 21;
  const u16* src = qkv + ((size_t)(b*1024 + n))*5120 + head*128 + dp*2;
  float e = bf2f(src[0]), od = bf2f(src[1]);
  float freq = exp2f((float)dp * -0.2076205059f);   // 10000^(-2dp/128)
  float ang = (float)n * freq;
  float c = cosf(ang), s = sinf(ang);
  const float QS = 0.12751747f;                     // (1/sqrt(128)) * log2(e)
  u16* dst = qr + (((size_t)(b*32 + head))*1024 + n)*128 + dp*2;
  dst[0] = f2bf((e*c - od*s)*QS);
  dst[1] = f2bf((od*c + e*s)*QS);
}

__global__ void rope_k(const u16* __restrict__ qkv, u16* __restrict__ kr) {
  int idx = blockIdx.x*256 + threadIdx.x;   // 1048576 pairs
  int dp = idx & 63;
  int kvh = (idx >> 6) & 3;
  int n = (idx >> 8) & 1023;
  int b = idx >> 18;
  const u16* src = qkv + ((size_t)(b*1024 + n))*5120 + 4096 + kvh*128 + dp*2;
  float e = bf2f(src[0]), od = bf2f(src[1]);
  float freq = exp2f((float)dp * -0.2076205059f);
  float ang = (float)n * freq;
  float c = cosf(ang), s = sinf(ang);
  u16* dst = kr + (((size_t)(b*4 + kvh))*1024 + n)*128 + dp*2;
  dst[0] = f2bf(e*c - od*s);
  dst[1] = f2bf(od*c + e*s);
}

// v cols of qkv_lin -> V^T (b, kvh, d=128, n=1024)
__global__ void vtrans(const u16* __restrict__ qkv, u16* __restrict__ vt) {
  __shared__ u16 t[32][40];
  const int nt = blockIdx.x, dt = blockIdx.y, bk = blockIdx.z;
  const int b = bk >> 2, kvh = bk & 3;
  const int tid = threadIdx.x;
  const int r = tid >> 3, c4 = (tid & 7)*4;
  const u16* src = qkv + ((size_t)(b*1024 + nt*32 + r))*5120 + 4608 + kvh*128 + dt*32 + c4;
#pragma unroll
  for (int i = 0; i < 4; ++i) t[r][c4 + i] = src[i];
  __syncthreads();
  u16* dst = vt + ((size_t)((b*4 + kvh)*128 + dt*32 + r))*1024 + nt*32 + c4;
#pragma unroll
  for (int i = 0; i < 4; ++i) dst[i] = t[c4 + i][r];
}

// ---------------------------------------------------------------------------
extern "C" void kernel_launch(void* const* d_in, const int* in_sizes, int n_in,
                              void* d_out, int out_size, void* d_ws, size_t ws_size,
                              hipStream_t stream) {
  const float* x  = (const float*)d_in[0];
  const float* Wq = (const float*)d_in[1];
  const float* bq = (const float*)d_in[2];
  const float* Wk = (const float*)d_in[3];
  const float* bk = (const float*)d_in[4];
  const float* Wv = (const float*)d_in[5];
  const float* bv = (const float*)d_in[6];
  const float* Wo = (const float*)d_in[7];
  const float* bo = (const float*)d_in[8];
  float* out = (float*)d_out;

  char* ws = (char*)d_ws;
  u16*   xb   = (u16*)(ws + 0);              // 33.5 MB  (x bf16)
  u16*   wqkv = (u16*)(ws + 33554432);       // 41.9 MB  (Wq^T|Wk^T|Wv^T bf16, 5120x4096)
  u16*   wo_t = (u16*)(ws + 75497472);       // 33.5 MB  (Wo^T bf16)
  float* bqkv = (float*)(ws + 109051904);    // 20 KB    (bq|bk|bv)
  u16*   qkvl = (u16*)(ws + 109072384);      // 41.9 MB  (qkv_lin bf16, 4096x5120)
  // dead-buffer reuse after QKV GEMM:
  u16*   qr   = (u16*)(ws + 33554432);       // over wqkv   (b,h,n,d)
  u16*   kr   = (u16*)(ws + 67108864);       //             (b,kvh,n,d)
  u16*   vt   = (u16*)(ws + 71303168);       //             (b,kvh,d,n)
  u16*   ctx  = (u16*)(ws + 0);              // over xb     (b*n, 4096)

  castx<<<16384, 256, 0, stream>>>(x, xb);
  wtrans<<<dim3(128,128), 256, 0, stream>>>(Wq, wqkv, 4096, 4096);
  wtrans<<<dim3(16,128),  256, 0, stream>>>(Wk, wqkv + (size_t)4096*4096, 4096, 512);
  wtrans<<<dim3(16,128),  256, 0, stream>>>(Wv, wqkv + (size_t)4608*4096, 4096, 512);
  wtrans<<<dim3(128,128), 256, 0, stream>>>(Wo, wo_t, 4096, 4096);
  packbias<<<20, 256, 0, stream>>>(bq, bk, bv, bqkv);

  gemm_bt<false><<<dim3(40,32), 256, 0, stream>>>(xb, wqkv, bqkv, qkvl, 4096, 5120, 4096);

  rope_q<<<32768, 256, 0, stream>>>(qkvl, qr);
  rope_k<<<4096,  256, 0, stream>>>(qkvl, kr);
  vtrans<<<dim3(32,4,16), 256, 0, stream>>>(qkvl, vt);

  attn<<<dim3(16,128), 256, 0, stream>>>(qr, kr, vt, ctx);

  gemm_bt<true><<<dim3(32,32), 256, 0, stream>>>(ctx, wo_t, bo, out, 4096, 4096, 4096);
}

// Round 2
// 874.405 us; speedup vs baseline: 1.0009x; 1.0009x over previous
//
#include <hip/hip_runtime.h>
#include <cstdint>
#include <cstddef>

typedef unsigned short u16;
typedef unsigned int u32;

typedef __bf16 bf16x8 __attribute__((ext_vector_type(8)));
typedef float f32x4 __attribute__((ext_vector_type(4)));

__device__ __forceinline__ u16 f2bf(float f) {
  union { float f; u32 u; } v; v.f = f;
  u32 r = v.u + 0x7fffu + ((v.u >> 16) & 1u);   // RNE
  return (u16)(r >> 16);
}
__device__ __forceinline__ float bf2f(u16 h) {
  union { u32 u; float f; } v; v.u = ((u32)h) << 16;
  return v.f;
}

// async global->LDS, 16B per lane; LDS dest = wave-uniform base + lane*16
__device__ __forceinline__ void gld16(const u16* g, u16* l) {
  __builtin_amdgcn_global_load_lds((const __attribute__((address_space(1))) u32*)g,
                                   (__attribute__((address_space(3))) u32*)l,
                                   16, 0, 0);
}

// ---------------------------------------------------------------------------
// GEMM: C(M,N) = A(M,K)bf16 * Bt(N,K)bf16^T + bias, 128x128 tiles, BK=64.
// LDS chunk layout (8-elem chunks, 8 chunks/row): slot(r,c) = r*8 + (c^(r&7)).
// Two barriers per BK=64 (half the drains of the BK=32 version); fragments
// loaded per k-sub-step to keep live VGPRs (and occupancy) unchanged.
// ---------------------------------------------------------------------------
template<bool OUT_F32>
__global__ __launch_bounds__(256)
void gemm_bt(const u16* __restrict__ A, const u16* __restrict__ Bt,
             const float* __restrict__ bias, void* __restrict__ C,
             int M, int N, int K) {
  __shared__ __attribute__((aligned(16))) u16 As[128*64];
  __shared__ __attribute__((aligned(16))) u16 Bs[128*64];
  const int tid  = threadIdx.x;
  const int lane = tid & 63;
  const int wave = tid >> 6;
  const int wm = wave >> 1, wn = wave & 1;
  const int bn = blockIdx.x * 128;
  const int bm = blockIdx.y * 128;
  const int kq = lane >> 4, ml = lane & 15;

  f32x4 acc[4][4] = {};

  for (int k0 = 0; k0 < K; k0 += 64) {
    __syncthreads();
#pragma unroll
    for (int j = 0; j < 4; ++j) {
      int s = wave*256 + j*64 + lane;
      int r = s >> 3;
      int c = (s & 7) ^ (r & 7);
      gld16(A  + (size_t)(bm + r)*K + k0 + c*8, As + (size_t)(wave*256 + j*64)*8);
      gld16(Bt + (size_t)(bn + r)*K + k0 + c*8, Bs + (size_t)(wave*256 + j*64)*8);
    }
    __syncthreads();
#pragma unroll
    for (int ks = 0; ks < 2; ++ks) {
      bf16x8 af[4], bfr[4];
#pragma unroll
      for (int t = 0; t < 4; ++t) {
        int ra = wm*64 + t*16 + ml;
        af[t]  = *(const bf16x8*)(As + (size_t)(ra*8 + ((ks*4 + kq) ^ (ra & 7)))*8);
        int rb = wn*64 + t*16 + ml;
        bfr[t] = *(const bf16x8*)(Bs + (size_t)(rb*8 + ((ks*4 + kq) ^ (rb & 7)))*8);
      }
#pragma unroll
      for (int i = 0; i < 4; ++i)
#pragma unroll
        for (int j = 0; j < 4; ++j)
          acc[i][j] = __builtin_amdgcn_mfma_f32_16x16x32_bf16(af[i], bfr[j], acc[i][j], 0, 0, 0);
    }
  }

  // C/D layout: col = lane&15, row = (lane>>4)*4 + reg   [m89/m91 verified]
#pragma unroll
  for (int i = 0; i < 4; ++i) {
    int rg0 = bm + wm*64 + i*16 + kq*4;
#pragma unroll
    for (int j = 0; j < 4; ++j) {
      int cg = bn + wn*64 + j*16 + ml;
      float bv = bias[cg];
#pragma unroll
      for (int r = 0; r < 4; ++r) {
        float v = acc[i][j][r] + bv;
        if (OUT_F32) ((float*)C)[(size_t)(rg0 + r)*N + cg] = v;
        else         ((u16*)C)[(size_t)(rg0 + r)*N + cg]   = f2bf(v);
      }
    }
  }
}

// ---------------------------------------------------------------------------
// Flash attention: grid (qt=16, b*32+head=128), block 256 (4 waves x 16 rows).
// Q pre-scaled by (1/sqrt(d))*log2(e); softmax via exp2.
// qt dispatched in DESCENDING order: diagonal (16-iteration) blocks start
// first -> better tail behavior for the triangular workload.
// ---------------------------------------------------------------------------
__global__ __launch_bounds__(256)
void attn(const u16* __restrict__ Q, const u16* __restrict__ K,
          const u16* __restrict__ V, u16* __restrict__ ctx) {
  __shared__ __attribute__((aligned(16))) u16 Qs[64*128];
  __shared__ __attribute__((aligned(16))) u16 Ks[64*128];
  __shared__ __attribute__((aligned(16))) u16 Vs[128*64];
  __shared__ __attribute__((aligned(16))) u16 Ps[4][16*72];  // pad 8: conflict-free A-reads
  const int qt  = (int)gridDim.x - 1 - (int)blockIdx.x;
  const int bh  = blockIdx.y;
  const int b   = bh >> 5;
  const int kvh = bh & 3;
  const int tid = threadIdx.x;
  const int lane = tid & 63;
  const int wave = tid >> 6;
  const int kq = lane >> 4, ml = lane & 15;

  const u16* Qg = Q + ((size_t)bh*1024 + qt*64)*128;
  const u16* Kg = K + ((size_t)(b*4 + kvh))*1024*128;
  const u16* Vg = V + ((size_t)(b*4 + kvh))*128*1024;

  // stage Q tile (64x128), swizzle slot = r*16 + (c ^ (r&7))
#pragma unroll
  for (int j = 0; j < 4; ++j) {
    int s = wave*256 + j*64 + lane;
    int r = s >> 4, c = (s & 15) ^ (r & 7);
    gld16(Qg + (size_t)r*128 + c*8, Qs + (size_t)(wave*256 + j*64)*8);
  }

  f32x4 o[8] = {};
  float m_i[4] = {-1e30f, -1e30f, -1e30f, -1e30f};
  float l_i[4] = {0.f, 0.f, 0.f, 0.f};

  for (int kt = 0; kt <= qt; ++kt) {
    __syncthreads();
#pragma unroll
    for (int j = 0; j < 4; ++j) {              // K tile 64x128
      int s = wave*256 + j*64 + lane;
      int r = s >> 4, c = (s & 15) ^ (r & 7);
      gld16(Kg + ((size_t)(kt*64 + r))*128 + c*8, Ks + (size_t)(wave*256 + j*64)*8);
    }
#pragma unroll
    for (int j = 0; j < 4; ++j) {              // V^T tile 128x64, slot = d*8 + (c ^ (d&7))
      int s = wave*256 + j*64 + lane;
      int d = s >> 3, c = (s & 7) ^ (d & 7);
      gld16(Vg + (size_t)d*1024 + kt*64 + c*8, Vs + (size_t)(wave*256 + j*64)*8);
    }
    __syncthreads();

    // S = Q * K^T  (16 rows x 64 cols per wave)
    f32x4 sf[4] = {};
#pragma unroll
    for (int ks = 0; ks < 4; ++ks) {
      int rq = wave*16 + ml;
      int cq = ks*4 + kq;
      bf16x8 aq = *(const bf16x8*)(Qs + (size_t)(rq*16 + (cq ^ (rq & 7)))*8);
#pragma unroll
      for (int nt = 0; nt < 4; ++nt) {
        int rk = nt*16 + ml;
        bf16x8 bk = *(const bf16x8*)(Ks + (size_t)(rk*16 + (cq ^ (rk & 7)))*8);
        sf[nt] = __builtin_amdgcn_mfma_f32_16x16x32_bf16(aq, bk, sf[nt], 0, 0, 0);
      }
    }

    const int i0 = qt*64 + wave*16 + kq*4;     // global q row of reg 0
    if (kt == qt) {                            // causal mask on diagonal tile
#pragma unroll
      for (int nt = 0; nt < 4; ++nt) {
        int jg = kt*64 + nt*16 + ml;
#pragma unroll
        for (int r = 0; r < 4; ++r)
          if (jg > i0 + r) sf[nt][r] = -1e30f;
      }
    }
    float rmax[4] = {-1e30f, -1e30f, -1e30f, -1e30f};
#pragma unroll
    for (int nt = 0; nt < 4; ++nt)
#pragma unroll
      for (int r = 0; r < 4; ++r)
        rmax[r] = fmaxf(rmax[r], sf[nt][r]);
#pragma unroll
    for (int r = 0; r < 4; ++r) {              // row-reduce across the 16 col-lanes
      float v = rmax[r];
      v = fmaxf(v, __shfl_xor(v, 1));
      v = fmaxf(v, __shfl_xor(v, 2));
      v = fmaxf(v, __shfl_xor(v, 4));
      v = fmaxf(v, __shfl_xor(v, 8));
      float mo = m_i[r];
      float mn = fmaxf(mo, v);
      m_i[r] = mn;
      rmax[r] = exp2f(mo - mn);                // alpha
    }
    float rsum[4] = {0.f, 0.f, 0.f, 0.f};
#pragma unroll
    for (int nt = 0; nt < 4; ++nt)
#pragma unroll
      for (int r = 0; r < 4; ++r) {
        float p = exp2f(sf[nt][r] - m_i[r]);
        rsum[r] += p;
        Ps[wave][(kq*4 + r)*72 + nt*16 + ml] = f2bf(p);
      }
#pragma unroll
    for (int r = 0; r < 4; ++r) {
      float v = rsum[r];
      v += __shfl_xor(v, 1);
      v += __shfl_xor(v, 2);
      v += __shfl_xor(v, 4);
      v += __shfl_xor(v, 8);
      l_i[r] = l_i[r]*rmax[r] + v;
    }
#pragma unroll
    for (int dt = 0; dt < 8; ++dt)
#pragma unroll
      for (int r = 0; r < 4; ++r)
        o[dt][r] *= rmax[r];
    __syncthreads();                           // P visible before PV reads

    // O += P(16x64) * V(64x128)
#pragma unroll
    for (int ks = 0; ks < 2; ++ks) {
      bf16x8 ap = *(const bf16x8*)(&Ps[wave][ml*72 + ks*32 + kq*8]);
#pragma unroll
      for (int dt = 0; dt < 8; ++dt) {
        int dv = dt*16 + ml;
        int cv = ks*4 + kq;
        bf16x8 bv = *(const bf16x8*)(Vs + (size_t)(dv*8 + (cv ^ (dv & 7)))*8);
        o[dt] = __builtin_amdgcn_mfma_f32_16x16x32_bf16(ap, bv, o[dt], 0, 0, 0);
      }
    }
  }

  const int head = bh & 31;
  float inv[4];
#pragma unroll
  for (int r = 0; r < 4; ++r) inv[r] = 1.f / l_i[r];
  size_t row0 = (size_t)b*1024 + qt*64 + wave*16 + kq*4;
#pragma unroll
  for (int dt = 0; dt < 8; ++dt) {
    int cg = head*128 + dt*16 + ml;
#pragma unroll
    for (int r = 0; r < 4; ++r)
      ctx[(row0 + r)*4096 + cg] = f2bf(o[dt][r]*inv[r]);
  }
}

// ---------------------------------------------------------------------------
// prep kernels
// ---------------------------------------------------------------------------
__global__ void castx(const float* __restrict__ x, u16* __restrict__ xb) {
  size_t i = ((size_t)blockIdx.x*256 + threadIdx.x)*4;
  float4 v = *(const float4*)(x + i);
  u16 o0 = f2bf(v.x), o1 = f2bf(v.y), o2 = f2bf(v.z), o3 = f2bf(v.w);
  ushort4 o; o.x = o0; o.y = o1; o.z = o2; o.w = o3;
  *(ushort4*)(xb + i) = o;
}

// W (K,N) f32 -> Wt (N,K) bf16, 32x32 LDS tile
__global__ void wtrans(const float* __restrict__ W, u16* __restrict__ Wt, int K, int N) {
  __shared__ u16 t[32][40];
  const int n0 = blockIdx.x*32, k0 = blockIdx.y*32;
  const int tid = threadIdx.x;
  const int r = tid >> 3, c4 = (tid & 7)*4;
  const float* src = W + (size_t)(k0 + r)*N + n0 + c4;
#pragma unroll
  for (int i = 0; i < 4; ++i) t[r][c4 + i] = f2bf(src[i]);
  __syncthreads();
  u16* dst = Wt + (size_t)(n0 + r)*K + k0 + c4;
#pragma unroll
  for (int i = 0; i < 4; ++i) dst[i] = t[c4 + i][r];
}

__global__ void packbias(const float* __restrict__ bq, const float* __restrict__ bk,
                         const float* __restrict__ bv, float* __restrict__ out) {
  int i = blockIdx.x*256 + threadIdx.x;
  float v;
  if (i < 4096)      v = bq[i];
  else if (i < 4608) v = bk[i - 4096];
  else               v = bv[i - 4608];
  out[i] = v;
}

// q cols of qkv_lin (ld 5120) -> (b, head, n, d) with RoPE, scaled by (1/sqrt(d))*log2e
__global__ void rope_q(const u16* __restrict__ qkv, u16* __restrict__ qr) {
  int idx = blockIdx.x*256 + threadIdx.x;   // 8388608 pairs
  int dp = idx & 63;
  int head = (idx >> 6) & 31;
  int n = (idx >> 11) & 1023;
  int b = idx >> 21;
  const u16* src = qkv + ((size_t)(b*1024 + n))*5120 + head*128 + dp*2;
  float e = bf2f(src[0]), od = bf2f(src[1]);
  float freq = exp2f((float)dp * -0.2076205059f);   // 10000^(-2dp/128)
  float ang = (float)n * freq;
  float c = cosf(ang), s = sinf(ang);
  const float QS = 0.12751747f;                     // (1/sqrt(128)) * log2(e)
  u16* dst = qr + (((size_t)(b*32 + head))*1024 + n)*128 + dp*2;
  dst[0] = f2bf((e*c - od*s)*QS);
  dst[1] = f2bf((od*c + e*s)*QS);
}

__global__ void rope_k(const u16* __restrict__ qkv, u16* __restrict__ kr) {
  int idx = blockIdx.x*256 + threadIdx.x;   // 1048576 pairs
  int dp = idx & 63;
  int kvh = (idx >> 6) & 3;
  int n = (idx >> 8) & 1023;
  int b = idx >> 18;
  const u16* src = qkv + ((size_t)(b*1024 + n))*5120 + 4096 + kvh*128 + dp*2;
  float e = bf2f(src[0]), od = bf2f(src[1]);
  float freq = exp2f((float)dp * -0.2076205059f);
  float ang = (float)n * freq;
  float c = cosf(ang), s = sinf(ang);
  u16* dst = kr + (((size_t)(b*4 + kvh))*1024 + n)*128 + dp*2;
  dst[0] = f2bf(e*c - od*s);
  dst[1] = f2bf(od*c + e*s);
}

// v cols of qkv_lin -> V^T (b, kvh, d=128, n=1024)
__global__ void vtrans(const u16* __restrict__ qkv, u16* __restrict__ vt) {
  __shared__ u16 t[32][40];
  const int nt = blockIdx.x, dt = blockIdx.y, bk = blockIdx.z;
  const int b = bk >> 2, kvh = bk & 3;
  const int tid = threadIdx.x;
  const int r = tid >> 3, c4 = (tid & 7)*4;
  const u16* src = qkv + ((size_t)(b*1024 + nt*32 + r))*5120 + 4608 + kvh*128 + dt*32 + c4;
#pragma unroll
  for (int i = 0; i < 4; ++i) t[r][c4 + i] = src[i];
  __syncthreads();
  u16* dst = vt + ((size_t)((b*4 + kvh)*128 + dt*32 + r))*1024 + nt*32 + c4;
#pragma unroll
  for (int i = 0; i < 4; ++i) dst[i] = t[c4 + i][r];
}

// ---------------------------------------------------------------------------
extern "C" void kernel_launch(void* const* d_in, const int* in_sizes, int n_in,
                              void* d_out, int out_size, void* d_ws, size_t ws_size,
                              hipStream_t stream) {
  const float* x  = (const float*)d_in[0];
  const float* Wq = (const float*)d_in[1];
  const float* bq = (const float*)d_in[2];
  const float* Wk = (const float*)d_in[3];
  const float* bk = (const float*)d_in[4];
  const float* Wv = (const float*)d_in[5];
  const float* bv = (const float*)d_in[6];
  const float* Wo = (const float*)d_in[7];
  const float* bo = (const float*)d_in[8];
  float* out = (float*)d_out;

  char* ws = (char*)d_ws;
  u16*   xb   = (u16*)(ws + 0);              // 33.5 MB  (x bf16)
  u16*   wqkv = (u16*)(ws + 33554432);       // 41.9 MB  (Wq^T|Wk^T|Wv^T bf16, 5120x4096)
  u16*   wo_t = (u16*)(ws + 75497472);       // 33.5 MB  (Wo^T bf16)
  float* bqkv = (float*)(ws + 109051904);    // 20 KB    (bq|bk|bv)
  u16*   qkvl = (u16*)(ws + 109072384);      // 41.9 MB  (qkv_lin bf16, 4096x5120)
  // dead-buffer reuse after QKV GEMM:
  u16*   qr   = (u16*)(ws + 33554432);       // over wqkv   (b,h,n,d)
  u16*   kr   = (u16*)(ws + 67108864);       //             (b,kvh,n,d)
  u16*   vt   = (u16*)(ws + 71303168);       //             (b,kvh,d,n)
  u16*   ctx  = (u16*)(ws + 0);              // over xb     (b*n, 4096)

  castx<<<16384, 256, 0, stream>>>(x, xb);
  wtrans<<<dim3(128,128), 256, 0, stream>>>(Wq, wqkv, 4096, 4096);
  wtrans<<<dim3(16,128),  256, 0, stream>>>(Wk, wqkv + (size_t)4096*4096, 4096, 512);
  wtrans<<<dim3(16,128),  256, 0, stream>>>(Wv, wqkv + (size_t)4608*4096, 4096, 512);
  wtrans<<<dim3(128,128), 256, 0, stream>>>(Wo, wo_t, 4096, 4096);
  packbias<<<20, 256, 0, stream>>>(bq, bk, bv, bqkv);

  gemm_bt<false><<<dim3(40,32), 256, 0, stream>>>(xb, wqkv, bqkv, qkvl, 4096, 5120, 4096);

  rope_q<<<32768, 256, 0, stream>>>(qkvl, qr);
  rope_k<<<4096,  256, 0, stream>>>(qkvl, kr);
  vtrans<<<dim3(32,4,16), 256, 0, stream>>>(qkvl, vt);

  attn<<<dim3(16,128), 256, 0, stream>>>(qr, kr, vt, ctx);

  gemm_bt<true><<<dim3(32,32), 256, 0, stream>>>(ctx, wo_t, bo, out, 4096, 4096, 4096);
}

// Round 3
// 838.806 us; speedup vs baseline: 1.0434x; 1.0424x over previous
//
#include <hip/hip_runtime.h>
#include <cstdint>
#include <cstddef>

typedef unsigned short u16;
typedef unsigned int u32;

typedef __bf16 bf16x8 __attribute__((ext_vector_type(8)));
typedef float f32x4 __attribute__((ext_vector_type(4)));
typedef u16 u16x8 __attribute__((ext_vector_type(8)));

__device__ __forceinline__ u16 f2bf(float f) {
  union { float f; u32 u; } v; v.f = f;
  u32 r = v.u + 0x7fffu + ((v.u >> 16) & 1u);   // RNE
  return (u16)(r >> 16);
}
__device__ __forceinline__ float bf2f(u16 h) {
  union { u32 u; float f; } v; v.u = ((u32)h) << 16;
  return v.f;
}

// async global->LDS, 16B per lane; LDS dest = wave-uniform base + lane*16
__device__ __forceinline__ void gld16(const u16* g, u16* l) {
  __builtin_amdgcn_global_load_lds((const __attribute__((address_space(1))) u32*)g,
                                   (__attribute__((address_space(3))) u32*)l,
                                   16, 0, 0);
}

// ---------------------------------------------------------------------------
// GEMM: C(M,N) = A(M,K)bf16 * Bt(N,K)bf16^T + bias, 128x128 tiles, BK=32,
// DOUBLE-BUFFERED LDS. Prefetch of tile k+1 is issued right AFTER the barrier
// and BEFORE computing tile k, so the vmcnt(0) drain at the next barrier waits
// on loads that are one full compute-phase old (latency hidden). Buffers are
// compile-time-indexed by unrolling 2 K-steps per loop body.
// LDS chunk swizzle: chunk(r,c) at slot r*4 + (c ^ ((r>>1)&3))  -> 0 conflicts.
// ---------------------------------------------------------------------------
template<bool OUT_F32>
__global__ __launch_bounds__(256)
void gemm_bt(const u16* __restrict__ A, const u16* __restrict__ Bt,
             const float* __restrict__ bias, void* __restrict__ C,
             int M, int N, int K) {
  __shared__ __attribute__((aligned(16))) u16 As[2][128*32];
  __shared__ __attribute__((aligned(16))) u16 Bs[2][128*32];
  const int tid  = threadIdx.x;
  const int lane = tid & 63;
  const int wave = tid >> 6;
  const int wm = wave >> 1, wn = wave & 1;
  const int bn = blockIdx.x * 128;
  const int bm = blockIdx.y * 128;
  const int kq = lane >> 4, ml = lane & 15;

  // per-lane staging addresses (j = 0,1), loop-invariant except +k0
  const u16* agp[2]; const u16* bgp[2]; int ldst[2];
#pragma unroll
  for (int j = 0; j < 2; ++j) {
    int s = wave*128 + j*64 + lane;
    int r = s >> 2;
    int c = (s & 3) ^ ((r >> 1) & 3);
    agp[j] = A  + (size_t)(bm + r)*K + c*8;
    bgp[j] = Bt + (size_t)(bn + r)*K + c*8;
    ldst[j] = (wave*128 + j*64)*8;
  }

  auto stage = [&](int p, int k0) {
#pragma unroll
    for (int j = 0; j < 2; ++j) {
      gld16(agp[j] + k0, &As[p][0] + ldst[j]);
      gld16(bgp[j] + k0, &Bs[p][0] + ldst[j]);
    }
  };

  f32x4 acc[4][4] = {};

  auto compute = [&](int p) {
    bf16x8 af[4], bfr[4];
#pragma unroll
    for (int t = 0; t < 4; ++t) {
      int ra = wm*64 + t*16 + ml;
      af[t]  = *(const bf16x8*)(&As[p][0] + (size_t)(ra*4 + (kq ^ ((ra >> 1) & 3)))*8);
      int rb = wn*64 + t*16 + ml;
      bfr[t] = *(const bf16x8*)(&Bs[p][0] + (size_t)(rb*4 + (kq ^ ((rb >> 1) & 3)))*8);
    }
#pragma unroll
    for (int i = 0; i < 4; ++i)
#pragma unroll
      for (int j = 0; j < 4; ++j)
        acc[i][j] = __builtin_amdgcn_mfma_f32_16x16x32_bf16(af[i], bfr[j], acc[i][j], 0, 0, 0);
  };

  stage(0, 0);
  for (int k0 = 0; k0 < K; k0 += 64) {          // K multiple of 64
    __syncthreads();                            // drain: tile k0 arrived; buf1 free
    if (k0 + 32 < K) stage(1, k0 + 32);         // prefetch next (overlaps compute)
    compute(0);
    __syncthreads();                            // drain: tile k0+32 arrived; buf0 free
    if (k0 + 64 < K) stage(0, k0 + 64);
    compute(1);
  }

  // C/D layout: col = lane&15, row = (lane>>4)*4 + reg   [m89/m91 verified]
#pragma unroll
  for (int i = 0; i < 4; ++i) {
    int rg0 = bm + wm*64 + i*16 + kq*4;
#pragma unroll
    for (int j = 0; j < 4; ++j) {
      int cg = bn + wn*64 + j*16 + ml;
      float bv = bias[cg];
#pragma unroll
      for (int r = 0; r < 4; ++r) {
        float v = acc[i][j][r] + bv;
        if (OUT_F32) ((float*)C)[(size_t)(rg0 + r)*N + cg] = v;
        else         ((u16*)C)[(size_t)(rg0 + r)*N + cg]   = f2bf(v);
      }
    }
  }
}

// ---------------------------------------------------------------------------
// Flash attention: grid (qt=16, b*32+head=128), block 256 (4 waves x 16 rows).
// Q pre-scaled by (1/sqrt(d))*log2(e); softmax via exp2. Descending qt order.
// ---------------------------------------------------------------------------
__global__ __launch_bounds__(256)
void attn(const u16* __restrict__ Q, const u16* __restrict__ K,
          const u16* __restrict__ V, u16* __restrict__ ctx) {
  __shared__ __attribute__((aligned(16))) u16 Qs[64*128];
  __shared__ __attribute__((aligned(16))) u16 Ks[64*128];
  __shared__ __attribute__((aligned(16))) u16 Vs[128*64];
  __shared__ __attribute__((aligned(16))) u16 Ps[4][16*72];  // pad 8: conflict-free A-reads
  const int qt  = (int)gridDim.x - 1 - (int)blockIdx.x;
  const int bh  = blockIdx.y;
  const int b   = bh >> 5;
  const int kvh = bh & 3;
  const int tid = threadIdx.x;
  const int lane = tid & 63;
  const int wave = tid >> 6;
  const int kq = lane >> 4, ml = lane & 15;

  const u16* Qg = Q + ((size_t)bh*1024 + qt*64)*128;
  const u16* Kg = K + ((size_t)(b*4 + kvh))*1024*128;
  const u16* Vg = V + ((size_t)(b*4 + kvh))*128*1024;

  // stage Q tile (64x128), swizzle slot = r*16 + (c ^ (r&7))
#pragma unroll
  for (int j = 0; j < 4; ++j) {
    int s = wave*256 + j*64 + lane;
    int r = s >> 4, c = (s & 15) ^ (r & 7);
    gld16(Qg + (size_t)r*128 + c*8, Qs + (size_t)(wave*256 + j*64)*8);
  }

  f32x4 o[8] = {};
  float m_i[4] = {-1e30f, -1e30f, -1e30f, -1e30f};
  float l_i[4] = {0.f, 0.f, 0.f, 0.f};

  for (int kt = 0; kt <= qt; ++kt) {
    __syncthreads();
#pragma unroll
    for (int j = 0; j < 4; ++j) {              // K tile 64x128
      int s = wave*256 + j*64 + lane;
      int r = s >> 4, c = (s & 15) ^ (r & 7);
      gld16(Kg + ((size_t)(kt*64 + r))*128 + c*8, Ks + (size_t)(wave*256 + j*64)*8);
    }
#pragma unroll
    for (int j = 0; j < 4; ++j) {              // V^T tile 128x64, slot = d*8 + (c ^ (d&7))
      int s = wave*256 + j*64 + lane;
      int d = s >> 3, c = (s & 7) ^ (d & 7);
      gld16(Vg + (size_t)d*1024 + kt*64 + c*8, Vs + (size_t)(wave*256 + j*64)*8);
    }
    __syncthreads();

    // S = Q * K^T  (16 rows x 64 cols per wave)
    f32x4 sf[4] = {};
#pragma unroll
    for (int ks = 0; ks < 4; ++ks) {
      int rq = wave*16 + ml;
      int cq = ks*4 + kq;
      bf16x8 aq = *(const bf16x8*)(Qs + (size_t)(rq*16 + (cq ^ (rq & 7)))*8);
#pragma unroll
      for (int nt = 0; nt < 4; ++nt) {
        int rk = nt*16 + ml;
        bf16x8 bk = *(const bf16x8*)(Ks + (size_t)(rk*16 + (cq ^ (rk & 7)))*8);
        sf[nt] = __builtin_amdgcn_mfma_f32_16x16x32_bf16(aq, bk, sf[nt], 0, 0, 0);
      }
    }

    const int i0 = qt*64 + wave*16 + kq*4;     // global q row of reg 0
    if (kt == qt) {                            // causal mask on diagonal tile
#pragma unroll
      for (int nt = 0; nt < 4; ++nt) {
        int jg = kt*64 + nt*16 + ml;
#pragma unroll
        for (int r = 0; r < 4; ++r)
          if (jg > i0 + r) sf[nt][r] = -1e30f;
      }
    }
    float rmax[4] = {-1e30f, -1e30f, -1e30f, -1e30f};
#pragma unroll
    for (int nt = 0; nt < 4; ++nt)
#pragma unroll
      for (int r = 0; r < 4; ++r)
        rmax[r] = fmaxf(rmax[r], sf[nt][r]);
#pragma unroll
    for (int r = 0; r < 4; ++r) {              // row-reduce across the 16 col-lanes
      float v = rmax[r];
      v = fmaxf(v, __shfl_xor(v, 1));
      v = fmaxf(v, __shfl_xor(v, 2));
      v = fmaxf(v, __shfl_xor(v, 4));
      v = fmaxf(v, __shfl_xor(v, 8));
      float mo = m_i[r];
      float mn = fmaxf(mo, v);
      m_i[r] = mn;
      rmax[r] = exp2f(mo - mn);                // alpha
    }
    float rsum[4] = {0.f, 0.f, 0.f, 0.f};
#pragma unroll
    for (int nt = 0; nt < 4; ++nt)
#pragma unroll
      for (int r = 0; r < 4; ++r) {
        float p = exp2f(sf[nt][r] - m_i[r]);
        rsum[r] += p;
        Ps[wave][(kq*4 + r)*72 + nt*16 + ml] = f2bf(p);
      }
#pragma unroll
    for (int r = 0; r < 4; ++r) {
      float v = rsum[r];
      v += __shfl_xor(v, 1);
      v += __shfl_xor(v, 2);
      v += __shfl_xor(v, 4);
      v += __shfl_xor(v, 8);
      l_i[r] = l_i[r]*rmax[r] + v;
    }
#pragma unroll
    for (int dt = 0; dt < 8; ++dt)
#pragma unroll
      for (int r = 0; r < 4; ++r)
        o[dt][r] *= rmax[r];
    __syncthreads();                           // P visible before PV reads

    // O += P(16x64) * V(64x128)
#pragma unroll
    for (int ks = 0; ks < 2; ++ks) {
      bf16x8 ap = *(const bf16x8*)(&Ps[wave][ml*72 + ks*32 + kq*8]);
#pragma unroll
      for (int dt = 0; dt < 8; ++dt) {
        int dv = dt*16 + ml;
        int cv = ks*4 + kq;
        bf16x8 bv = *(const bf16x8*)(Vs + (size_t)(dv*8 + (cv ^ (dv & 7)))*8);
        o[dt] = __builtin_amdgcn_mfma_f32_16x16x32_bf16(ap, bv, o[dt], 0, 0, 0);
      }
    }
  }

  const int head = bh & 31;
  float inv[4];
#pragma unroll
  for (int r = 0; r < 4; ++r) inv[r] = 1.f / l_i[r];
  size_t row0 = (size_t)b*1024 + qt*64 + wave*16 + kq*4;
#pragma unroll
  for (int dt = 0; dt < 8; ++dt) {
    int cg = head*128 + dt*16 + ml;
#pragma unroll
    for (int r = 0; r < 4; ++r)
      ctx[(row0 + r)*4096 + cg] = f2bf(o[dt][r]*inv[r]);
  }
}

// ---------------------------------------------------------------------------
// prep kernels
// ---------------------------------------------------------------------------
__global__ void castx(const float* __restrict__ x, u16* __restrict__ xb) {
  size_t i = ((size_t)blockIdx.x*256 + threadIdx.x)*4;
  float4 v = *(const float4*)(x + i);
  ushort4 o; o.x = f2bf(v.x); o.y = f2bf(v.y); o.z = f2bf(v.z); o.w = f2bf(v.w);
  *(ushort4*)(xb + i) = o;
}

// W (K,N) f32 -> Wt (N,K) bf16, 64x64 tiles, 256 threads.
// LDS pitch 71 u16: transposed reads are conflict-free (16a*71 dw-offsets
// {0,24,16,8} + n/2 cover all 32 banks).
__global__ void wtrans(const float* __restrict__ W, u16* __restrict__ Wt, int K, int N) {
  __shared__ u16 t[64*71 + 8];
  const int n0 = blockIdx.x*64, k0 = blockIdx.y*64;
  const int tid = threadIdx.x;
  const int kr = tid >> 4, nc = (tid & 15)*4;
#pragma unroll
  for (int i = 0; i < 4; ++i) {
    float4 v = *(const float4*)(W + (size_t)(k0 + kr + i*16)*N + n0 + nc);
    u16* d = &t[(kr + i*16)*71 + nc];
    d[0] = f2bf(v.x); d[1] = f2bf(v.y); d[2] = f2bf(v.z); d[3] = f2bf(v.w);
  }
  __syncthreads();
  const int n = tid >> 2, k16 = (tid & 3)*16;
  u16x8 lo, hi;
#pragma unroll
  for (int j = 0; j < 8; ++j) lo[j] = t[(k16 + j)*71 + n];
#pragma unroll
  for (int j = 0; j < 8; ++j) hi[j] = t[(k16 + 8 + j)*71 + n];
  u16* dst = Wt + (size_t)(n0 + n)*K + k0 + k16;
  *(u16x8*)(dst)     = lo;
  *(u16x8*)(dst + 8) = hi;
}

__global__ void packbias(const float* __restrict__ bq, const float* __restrict__ bk,
                         const float* __restrict__ bv, float* __restrict__ out) {
  int i = blockIdx.x*256 + threadIdx.x;
  float v;
  if (i < 4096)      v = bq[i];
  else if (i < 4608) v = bk[i - 4096];
  else               v = bv[i - 4608];
  out[i] = v;
}

// q cols of qkv_lin (ld 5120) -> (b, head, n, d) with RoPE, scaled by (1/sqrt(d))*log2e
__global__ void rope_q(const u16* __restrict__ qkv, u16* __restrict__ qr) {
  int idx = blockIdx.x*256 + threadIdx.x;   // 8388608 pairs
  int dp = idx & 63;
  int head = (idx >> 6) & 31;
  int n = (idx >> 11) & 1023;
  int b = idx >> 21;
  const u16* src = qkv + ((size_t)(b*1024 + n))*5120 + head*128 + dp*2;
  float e = bf2f(src[0]), od = bf2f(src[1]);
  float freq = exp2f((float)dp * -0.2076205059f);   // 10000^(-2dp/128)
  float ang = (float)n * freq;
  float c = cosf(ang), s = sinf(ang);
  const float QS = 0.12751747f;                     // (1/sqrt(128)) * log2(e)
  u16* dst = qr + (((size_t)(b*32 + head))*1024 + n)*128 + dp*2;
  dst[0] = f2bf((e*c - od*s)*QS);
  dst[1] = f2bf((od*c + e*s)*QS);
}

__global__ void rope_k(const u16* __restrict__ qkv, u16* __restrict__ kr) {
  int idx = blockIdx.x*256 + threadIdx.x;   // 1048576 pairs
  int dp = idx & 63;
  int kvh = (idx >> 6) & 3;
  int n = (idx >> 8) & 1023;
  int b = idx >> 18;
  const u16* src = qkv + ((size_t)(b*1024 + n))*5120 + 4096 + kvh*128 + dp*2;
  float e = bf2f(src[0]), od = bf2f(src[1]);
  float freq = exp2f((float)dp * -0.2076205059f);
  float ang = (float)n * freq;
  float c = cosf(ang), s = sinf(ang);
  u16* dst = kr + (((size_t)(b*4 + kvh))*1024 + n)*128 + dp*2;
  dst[0] = f2bf(e*c - od*s);
  dst[1] = f2bf(od*c + e*s);
}

// v cols of qkv_lin -> V^T (b, kvh, d=128, n=1024)
__global__ void vtrans(const u16* __restrict__ qkv, u16* __restrict__ vt) {
  __shared__ u16 t[32][40];
  const int nt = blockIdx.x, dt = blockIdx.y, bk = blockIdx.z;
  const int b = bk >> 2, kvh = bk & 3;
  const int tid = threadIdx.x;
  const int r = tid >> 3, c4 = (tid & 7)*4;
  const u16* src = qkv + ((size_t)(b*1024 + nt*32 + r))*5120 + 4608 + kvh*128 + dt*32 + c4;
#pragma unroll
  for (int i = 0; i < 4; ++i) t[r][c4 + i] = src[i];
  __syncthreads();
  u16* dst = vt + ((size_t)((b*4 + kvh)*128 + dt*32 + r))*1024 + nt*32 + c4;
#pragma unroll
  for (int i = 0; i < 4; ++i) dst[i] = t[c4 + i][r];
}

// ---------------------------------------------------------------------------
extern "C" void kernel_launch(void* const* d_in, const int* in_sizes, int n_in,
                              void* d_out, int out_size, void* d_ws, size_t ws_size,
                              hipStream_t stream) {
  const float* x  = (const float*)d_in[0];
  const float* Wq = (const float*)d_in[1];
  const float* bq = (const float*)d_in[2];
  const float* Wk = (const float*)d_in[3];
  const float* bk = (const float*)d_in[4];
  const float* Wv = (const float*)d_in[5];
  const float* bv = (const float*)d_in[6];
  const float* Wo = (const float*)d_in[7];
  const float* bo = (const float*)d_in[8];
  float* out = (float*)d_out;

  char* ws = (char*)d_ws;
  u16*   xb   = (u16*)(ws + 0);              // 33.5 MB  (x bf16)
  u16*   wqkv = (u16*)(ws + 33554432);       // 41.9 MB  (Wq^T|Wk^T|Wv^T bf16, 5120x4096)
  u16*   wo_t = (u16*)(ws + 75497472);       // 33.5 MB  (Wo^T bf16)
  float* bqkv = (float*)(ws + 109051904);    // 20 KB    (bq|bk|bv)
  u16*   qkvl = (u16*)(ws + 109072384);      // 41.9 MB  (qkv_lin bf16, 4096x5120)
  // dead-buffer reuse after QKV GEMM:
  u16*   qr   = (u16*)(ws + 33554432);       // over wqkv   (b,h,n,d)
  u16*   kr   = (u16*)(ws + 67108864);       //             (b,kvh,n,d)
  u16*   vt   = (u16*)(ws + 71303168);       //             (b,kvh,d,n)
  u16*   ctx  = (u16*)(ws + 0);              // over xb     (b*n, 4096)

  castx<<<16384, 256, 0, stream>>>(x, xb);
  wtrans<<<dim3(64,64), 256, 0, stream>>>(Wq, wqkv, 4096, 4096);
  wtrans<<<dim3(8,64),  256, 0, stream>>>(Wk, wqkv + (size_t)4096*4096, 4096, 512);
  wtrans<<<dim3(8,64),  256, 0, stream>>>(Wv, wqkv + (size_t)4608*4096, 4096, 512);
  wtrans<<<dim3(64,64), 256, 0, stream>>>(Wo, wo_t, 4096, 4096);
  packbias<<<20, 256, 0, stream>>>(bq, bk, bv, bqkv);

  gemm_bt<false><<<dim3(40,32), 256, 0, stream>>>(xb, wqkv, bqkv, qkvl, 4096, 5120, 4096);

  rope_q<<<32768, 256, 0, stream>>>(qkvl, qr);
  rope_k<<<4096,  256, 0, stream>>>(qkvl, kr);
  vtrans<<<dim3(32,4,16), 256, 0, stream>>>(qkvl, vt);

  attn<<<dim3(16,128), 256, 0, stream>>>(qr, kr, vt, ctx);

  gemm_bt<true><<<dim3(32,32), 256, 0, stream>>>(ctx, wo_t, bo, out, 4096, 4096, 4096);
}